// Round 1
// baseline (269.874 us; speedup 1.0000x reference)
//
#include <hip/hip_runtime.h>
#include <math.h>

#define BB 4
#define SS 4096
#define DD 1024
#define HH 16
#define GG 4
#define KK 3
#define DG 256
#define DH 64

// ---- workspace layout (float offsets, all float4-aligned) ----
enum : size_t {
  OFF_WEFF  = 0,        // DG*KK = 768
  OFF_OFFC  = 1024,     // 4
  OFF_WEQ   = 1280,     // 12*DD = 12288   [j=g*3+k][c]
  OFF_ZT    = 13568,    // B*S*12 = 196608 [b][s][j]
  OFF_WX    = 210176,   // B*G*S = 65536   [b][g][s]
  OFF_XWP   = 275712,   // B*64*G*D = 1048576 partials
  OFF_XSP   = 1324288,  // B*64*D = 262144 partials
  OFF_XW    = 1586432,  // B*G*D = 16384   [b][g][c]
  OFF_XS    = 1602816,  // B*D = 4096
  OFF_SW    = 1606912,  // B*G = 16 (padded)
  OFF_FEAT  = 1607168,  // B*D = 4096
  OFF_KF    = 1611264,  // B*G*D = 16384   [b][g][o]
  OFF_VF    = 1627648,  // B*G*D = 16384
  OFF_QW    = 1644032,  // B*D*G = 16384   [b][I][g]
  OFF_QS    = 1660416,  // B*D = 4096
  OFF_AV    = 1664512,  // B*D*G = 16384   [b][d][g]
  OFF_AB    = 1680896,  // B*D = 4096
  OFF_C2    = 1684992,  // B*D = 4096
  OFF_WAV   = 1689088,  // B*D*G = 16384   [b][o][g]
  OFF_WOSUM = 1705472,  // D = 1024
  WS_FLOATS = 1706496   // ~6.5 MB
};

__device__ __forceinline__ float wred_sum(float v) {
#pragma unroll
  for (int o = 32; o > 0; o >>= 1) v += __shfl_xor(v, o, 64);
  return v;
}
__device__ __forceinline__ float wred_max(float v) {
#pragma unroll
  for (int o = 32; o > 0; o >>= 1) v = fmaxf(v, __shfl_xor(v, o, 64));
  return v;
}

// ---- K0a: Weff[i][k] = sum_cc Woff2[cc] * Woff1[cc,i,k] ----
__global__ void k_weff(const float* __restrict__ Woff1, const float* __restrict__ Woff2,
                       float* __restrict__ ws) {
  int tid = blockIdx.x * blockDim.x + threadIdx.x;
  if (tid >= DG * KK) return;
  int i = tid / KK, kk = tid - KK * i;
  float a = 0.f;
  for (int cc = 0; cc < DG; ++cc)
    a += Woff2[cc] * Woff1[(cc * DG + i) * KK + kk];
  ws[OFF_WEFF + tid] = a;
}

// ---- K0b: Weq[j=g*3+k][c] = sum_i Weff[i,k]*Wq[g*DG+i, c]; offc[g] ----
__global__ void k_weq(const float* __restrict__ Wq, const float* __restrict__ bq,
                      const float* __restrict__ Woff2, const float* __restrict__ boff1,
                      float* __restrict__ ws) {
  const float* Weff = ws + OFF_WEFF;
  int gid = blockIdx.x * blockDim.x + threadIdx.x;
  if (gid < 12 * DD) {
    int c = gid & (DD - 1);
    int j = gid >> 10;           // j = g*3+kk
    int g = j / 3, kk = j - 3 * g;
    float a = 0.f;
    for (int i = 0; i < DG; ++i)
      a += Weff[i * KK + kk] * Wq[(size_t)(g * DG + i) * DD + c];
    ws[OFF_WEQ + gid] = a;
  } else if (gid < 12 * DD + GG) {
    int g = gid - 12 * DD;
    float a = 0.f;
    for (int cc = 0; cc < DG; ++cc) a += Woff2[cc] * boff1[cc];  // beff
    for (int i = 0; i < DG; ++i)
      for (int kk = 0; kk < KK; ++kk)
        a += Weff[i * KK + kk] * bq[g * DG + i];
    ws[OFF_OFFC + g] = a;
  }
}

// ---- K1a: zt[b][s][j] = Weq[j,:] . x[b,s,:]  (12 dots of 1024 per row) ----
// Weq held in registers (192 VGPR), wave per row, grid-stride. HBM-bound: 67 MB read.
__global__ __launch_bounds__(256, 2) void k_z(const float* __restrict__ x,
                                              const float* __restrict__ weq,
                                              float* __restrict__ zt) {
  const int lane = threadIdx.x & 63;
  const int wave = (blockIdx.x * blockDim.x + threadIdx.x) >> 6;
  const int nwaves = (gridDim.x * blockDim.x) >> 6;
  float4 w[12][4];
#pragma unroll
  for (int j = 0; j < 12; ++j)
#pragma unroll
    for (int it = 0; it < 4; ++it)
      w[j][it] = *(const float4*)(weq + (size_t)j * DD + 4 * (lane + 64 * it));
  for (int row = wave; row < BB * SS; row += nwaves) {
    const float4* xr = (const float4*)(x + (size_t)row * DD);
    float4 xv[4];
#pragma unroll
    for (int it = 0; it < 4; ++it) xv[it] = xr[lane + 64 * it];
    float acc[12];
#pragma unroll
    for (int j = 0; j < 12; ++j) {
      float a = 0.f;
#pragma unroll
      for (int it = 0; it < 4; ++it)
        a += xv[it].x * w[j][it].x + xv[it].y * w[j][it].y +
             xv[it].z * w[j][it].z + xv[it].w * w[j][it].w;
      acc[j] = a;
    }
#pragma unroll
    for (int j = 0; j < 12; ++j) acc[j] = wred_sum(acc[j]);
    if (lane == 0) {
#pragma unroll
      for (int j = 0; j < 12; ++j) zt[(size_t)row * 12 + j] = acc[j];
    }
  }
}

// ---- K1b: offset -> tanh -> wx  (conv k=3 pad=1 over zt) ----
__global__ void k_wx(float* __restrict__ ws) {
  const int gid = blockIdx.x * blockDim.x + threadIdx.x;
  if (gid >= BB * GG * SS) return;
  const int s = gid & (SS - 1);
  const int g = (gid >> 12) & 3;
  const int b = gid >> 14;
  const float* z = ws + OFF_ZT + (size_t)b * SS * 12;
  float off = ws[OFF_OFFC + g];
  if (s > 0)      off += z[(size_t)(s - 1) * 12 + g * 3 + 0];
  off += z[(size_t)s * 12 + g * 3 + 1];
  if (s < SS - 1) off += z[(size_t)(s + 1) * 12 + g * 3 + 2];
  off = tanhf(off) * (float)KK;
  const float vg = 2.0f * ((float)s + off) / (float)(SS - 1) - 1.0f;
  const float ix = 0.5f * vg;
  float wv = 1.0f - fabsf(ix);
  wv = fminf(fmaxf(wv, 0.0f), 1.0f);
  ws[OFF_WX + (size_t)(b * GG + g) * SS + s] = wv;
}

// ---- K2: partial Xw[b,g,c] = sum_s x*wx, Xs[b,c] = sum_s x (64 s-rows per block) ----
__global__ void k_xw_part(const float* __restrict__ x, float* __restrict__ ws) {
  const float* wx = ws + OFF_WX;
  const int b = blockIdx.x >> 6;
  const int ch = blockIdx.x & 63;
  const int t = threadIdx.x;
  float aw[4][4] = {};
  float as[4] = {};
  const int s0 = ch * 64;
  for (int si = 0; si < 64; ++si) {
    const int s = s0 + si;
    const float w0 = wx[(size_t)(b * GG + 0) * SS + s];
    const float w1 = wx[(size_t)(b * GG + 1) * SS + s];
    const float w2 = wx[(size_t)(b * GG + 2) * SS + s];
    const float w3 = wx[(size_t)(b * GG + 3) * SS + s];
    const float* xr = x + (size_t)(b * SS + s) * DD;
#pragma unroll
    for (int ic = 0; ic < 4; ++ic) {
      const float f = xr[t + 256 * ic];
      as[ic] += f;
      aw[ic][0] += f * w0; aw[ic][1] += f * w1;
      aw[ic][2] += f * w2; aw[ic][3] += f * w3;
    }
  }
  float* Xwp = ws + OFF_XWP;
  float* Xsp = ws + OFF_XSP;
#pragma unroll
  for (int ic = 0; ic < 4; ++ic) {
    const int c = t + 256 * ic;
#pragma unroll
    for (int g = 0; g < 4; ++g)
      Xwp[((size_t)(b * 64 + ch) * GG + g) * DD + c] = aw[ic][g];
    Xsp[(size_t)(b * 64 + ch) * DD + c] = as[ic];
  }
}

// ---- K2b: reduce partials -> Xw, Xs; Sw[b,g] = sum_s wx ----
__global__ void k_xw_red(float* __restrict__ ws) {
  const int gid = blockIdx.x * blockDim.x + threadIdx.x;
  const float* Xwp = ws + OFF_XWP;
  const float* Xsp = ws + OFF_XSP;
  if (gid < BB * GG * DD) {                      // 16384
    const int c = gid & 1023, g = (gid >> 10) & 3, b = gid >> 12;
    float a = 0.f;
    for (int ch = 0; ch < 64; ++ch)
      a += Xwp[((size_t)(b * 64 + ch) * GG + g) * DD + c];
    ws[OFF_XW + gid] = a;
  } else if (gid < BB * GG * DD + BB * DD) {     // +4096
    const int i = gid - BB * GG * DD;
    const int c = i & 1023, b = i >> 10;
    float a = 0.f;
    for (int ch = 0; ch < 64; ++ch)
      a += Xsp[(size_t)(b * 64 + ch) * DD + c];
    ws[OFF_XS + i] = a;
  } else if (gid < BB * GG * DD + BB * DD + 16 * 64) {  // 16 waves for Sw
    const int i = gid - (BB * GG * DD + BB * DD);
    const int lane = i & 63, w = i >> 6;         // w = b*4+g
    const float* wx = ws + OFF_WX;
    float a = 0.f;
    for (int s = lane; s < SS; s += 64) a += wx[(size_t)w * SS + s];
    a = wred_sum(a);
    if (lane == 0) ws[OFF_SW + w] = a;
  }
}

// ---- K3a: feat[b,c] = 0.5*(x[b,2047,c] + x[b,2048,c]) ----
__global__ void k_feat(const float* __restrict__ x, float* __restrict__ ws) {
  int gid = blockIdx.x * blockDim.x + threadIdx.x;
  if (gid >= BB * DD) return;
  int b = gid >> 10, c = gid & 1023;
  ws[OFF_FEAT + gid] = 0.5f * (x[((size_t)b * SS + 2047) * DD + c] +
                               x[((size_t)b * SS + 2048) * DD + c]);
}

// ---- K3b: all small dot-products, one wave per output ----
// [0,16384): Kf   [16384,32768): Vf   [32768,49152): Qw
// [49152,53248): Qs   [53248,54272): WoSum
__global__ void k_dots(const float* __restrict__ Wq, const float* __restrict__ bq,
                       const float* __restrict__ Wk, const float* __restrict__ Wv,
                       const float* __restrict__ Wo, float* __restrict__ ws) {
  const int lane = threadIdx.x & 63;
  const int w = (blockIdx.x * blockDim.x + threadIdx.x) >> 6;
  if (w < 16384) {                               // Kf[b][g][o]
    const int o = w & 1023, g = (w >> 10) & 3, b = w >> 12;
    const float4 a = ((const float4*)(Wk + (size_t)o * DD + g * DG))[lane];
    const float4 f = ((const float4*)(ws + OFF_FEAT + b * DD + g * DG))[lane];
    float v = a.x * f.x + a.y * f.y + a.z * f.z + a.w * f.w;
    v = wred_sum(v);
    if (lane == 0) ws[OFF_KF + w] = v;
  } else if (w < 32768) {                        // Vf[b][g][o]
    const int i2 = w - 16384;
    const int o = i2 & 1023, g = (i2 >> 10) & 3, b = i2 >> 12;
    const float4 a = ((const float4*)(Wv + (size_t)o * DD + g * DG))[lane];
    const float4 f = ((const float4*)(ws + OFF_FEAT + b * DD + g * DG))[lane];
    float v = a.x * f.x + a.y * f.y + a.z * f.z + a.w * f.w;
    v = wred_sum(v);
    if (lane == 0) ws[OFF_VF + i2] = v;
  } else if (w < 49152) {                        // Qw[b][I][g]
    const int i2 = w - 32768;
    const int g = i2 & 3, I = (i2 >> 2) & 1023, b = i2 >> 12;
    const float4* wq = (const float4*)(Wq + (size_t)I * DD);
    const float4* xw = (const float4*)(ws + OFF_XW + (size_t)(b * GG + g) * DD);
    float v = 0.f;
#pragma unroll
    for (int it = 0; it < 4; ++it) {
      const float4 a = wq[lane + 64 * it], c = xw[lane + 64 * it];
      v += a.x * c.x + a.y * c.y + a.z * c.z + a.w * c.w;
    }
    v = wred_sum(v);
    if (lane == 0) ws[OFF_QW + i2] = v + bq[I] * ws[OFF_SW + b * GG + g];
  } else if (w < 53248) {                        // Qs[b][I]
    const int i2 = w - 49152;
    const int I = i2 & 1023, b = i2 >> 10;
    const float4* wq = (const float4*)(Wq + (size_t)I * DD);
    const float4* xs = (const float4*)(ws + OFF_XS + (size_t)b * DD);
    float v = 0.f;
#pragma unroll
    for (int it = 0; it < 4; ++it) {
      const float4 a = wq[lane + 64 * it], c = xs[lane + 64 * it];
      v += a.x * c.x + a.y * c.y + a.z * c.z + a.w * c.w;
    }
    v = wred_sum(v);
    if (lane == 0) ws[OFF_QS + i2] = v + (float)SS * bq[I];
  } else if (w < 54272) {                        // WoSum[o]
    const int o = w - 53248;
    const float4* wo = (const float4*)(Wo + (size_t)o * DD);
    float v = 0.f;
#pragma unroll
    for (int it = 0; it < 4; ++it) {
      const float4 a = wo[lane + 64 * it];
      v += a.x + a.y + a.z + a.w;
    }
    v = wred_sum(v);
    if (lane == 0) ws[OFF_WOSUM + o] = v;
  }
}

// ---- K4: scores -> softmax -> AV, Ab. One wave per (b, d) row; lane = j ----
__global__ void k_attn(const float* __restrict__ bk, const float* __restrict__ bv,
                       float* __restrict__ ws) {
  const int gid = blockIdx.x * blockDim.x + threadIdx.x;
  const int lane = gid & 63;
  const int w = gid >> 6;                        // w = b*1024 + d
  if (w >= BB * DD) return;
  const int b = w >> 10, d = w & 1023;
  const int hh = d >> 6;
  const int J = (hh << 6) | lane;
  const float* Qw = ws + OFF_QW + (size_t)w * 4;
  const float q0 = Qw[0], q1 = Qw[1], q2 = Qw[2], q3 = Qw[3];
  const float qs = ws[OFF_QS + w];
  const float* Kf = ws + OFF_KF + (size_t)b * GG * DD;
  float sc = q0 * Kf[0 * DD + J] + q1 * Kf[1 * DD + J] +
             q2 * Kf[2 * DD + J] + q3 * Kf[3 * DD + J] + bk[J] * qs;
  sc *= 0.03125f;                                // D^-0.5 = 1/32
  const float m = wred_max(sc);
  const float e = expf(sc - m);
  const float sum = wred_sum(e);
  const float attn = e / sum;
  const float* Vf = ws + OFF_VF + (size_t)b * GG * DD;
#pragma unroll
  for (int g = 0; g < 4; ++g) {
    const float av = wred_sum(attn * Vf[(size_t)g * DD + J]);
    if (lane == 0) ws[OFF_AV + (size_t)w * 4 + g] = av;
  }
  const float ab = wred_sum(attn * bv[J]);
  if (lane == 0) ws[OFF_AB + w] = ab;
}

// ---- K5: WAV[b,o,g] = sum_d Wo[o,d]*AV[b,d,g]; C2 = sum_d Wo*Ab + bo ----
__global__ void k_wav(const float* __restrict__ Wo, const float* __restrict__ bo,
                      float* __restrict__ ws) {
  const int gid = blockIdx.x * blockDim.x + threadIdx.x;
  const int lane = gid & 63;
  const int w = gid >> 6;                        // w = b*1024 + o
  if (w >= BB * DD) return;
  const int b = w >> 10, o = w & 1023;
  float acc0 = 0, acc1 = 0, acc2 = 0, acc3 = 0, acc4 = 0;
  const float4* wo4 = (const float4*)(Wo + (size_t)o * DD);
  const float* AV = ws + OFF_AV + (size_t)b * DD * 4;
  const float* Ab = ws + OFF_AB + (size_t)b * DD;
#pragma unroll
  for (int it = 0; it < 4; ++it) {
    const int d4 = lane + 64 * it;               // d = 4*d4 .. 4*d4+3
    const float4 wv = wo4[d4];
    const float4 a0 = *(const float4*)(AV + (size_t)(4 * d4 + 0) * 4);
    const float4 a1 = *(const float4*)(AV + (size_t)(4 * d4 + 1) * 4);
    const float4 a2 = *(const float4*)(AV + (size_t)(4 * d4 + 2) * 4);
    const float4 a3 = *(const float4*)(AV + (size_t)(4 * d4 + 3) * 4);
    acc0 += wv.x * a0.x + wv.y * a1.x + wv.z * a2.x + wv.w * a3.x;
    acc1 += wv.x * a0.y + wv.y * a1.y + wv.z * a2.y + wv.w * a3.y;
    acc2 += wv.x * a0.z + wv.y * a1.z + wv.z * a2.z + wv.w * a3.z;
    acc3 += wv.x * a0.w + wv.y * a1.w + wv.z * a2.w + wv.w * a3.w;
    const float4 abv = *(const float4*)(Ab + 4 * d4);
    acc4 += wv.x * abv.x + wv.y * abv.y + wv.z * abv.z + wv.w * abv.w;
  }
  acc0 = wred_sum(acc0); acc1 = wred_sum(acc1); acc2 = wred_sum(acc2);
  acc3 = wred_sum(acc3); acc4 = wred_sum(acc4);
  if (lane == 0) {
    float* WAV = ws + OFF_WAV + (size_t)w * 4;
    WAV[0] = acc0; WAV[1] = acc1; WAV[2] = acc2; WAV[3] = acc3;
    ws[OFF_C2 + w] = acc4 + bo[o];
  }
}

// ---- K6: out[b,s,o] = sum_g wx*WAV + C2 + bias_table[s]*WoSum ----
__global__ __launch_bounds__(256) void k_out(const float* __restrict__ btab,
                                             const float* __restrict__ ws,
                                             float* __restrict__ out) {
  const int b = blockIdx.x >> 6;
  const int ch = blockIdx.x & 63;
  const int t = threadIdx.x;
  const int o0 = 4 * t;
  float4 wav[4];
#pragma unroll
  for (int io = 0; io < 4; ++io)
    wav[io] = *(const float4*)(ws + OFF_WAV + (size_t)(b * DD + o0 + io) * 4);
  const float4 c24 = *(const float4*)(ws + OFF_C2 + (size_t)b * DD + o0);
  const float4 wos4 = *(const float4*)(ws + OFF_WOSUM + o0);
  const float* wx = ws + OFF_WX;
  const int s0 = ch * 64;
  for (int si = 0; si < 64; ++si) {
    const int s = s0 + si;
    const float w0 = wx[(size_t)(b * GG + 0) * SS + s];
    const float w1 = wx[(size_t)(b * GG + 1) * SS + s];
    const float w2 = wx[(size_t)(b * GG + 2) * SS + s];
    const float w3 = wx[(size_t)(b * GG + 3) * SS + s];
    const float bt = btab[s];
    float4 val;
    val.x = c24.x + bt * wos4.x + w0 * wav[0].x + w1 * wav[0].y + w2 * wav[0].z + w3 * wav[0].w;
    val.y = c24.y + bt * wos4.y + w0 * wav[1].x + w1 * wav[1].y + w2 * wav[1].z + w3 * wav[1].w;
    val.z = c24.z + bt * wos4.z + w0 * wav[2].x + w1 * wav[2].y + w2 * wav[2].z + w3 * wav[2].w;
    val.w = c24.w + bt * wos4.w + w0 * wav[3].x + w1 * wav[3].y + w2 * wav[3].z + w3 * wav[3].w;
    *(float4*)(out + (size_t)(b * SS + s) * DD + o0) = val;
  }
}

extern "C" void kernel_launch(void* const* d_in, const int* in_sizes, int n_in,
                              void* d_out, int out_size, void* d_ws, size_t ws_size,
                              hipStream_t stream) {
  const float* x     = (const float*)d_in[0];
  const float* Wq    = (const float*)d_in[1];
  const float* bq    = (const float*)d_in[2];
  const float* Wk    = (const float*)d_in[3];
  const float* bk    = (const float*)d_in[4];
  const float* Wv    = (const float*)d_in[5];
  const float* bv    = (const float*)d_in[6];
  const float* Wo    = (const float*)d_in[7];
  const float* bo    = (const float*)d_in[8];
  const float* Woff1 = (const float*)d_in[9];
  const float* boff1 = (const float*)d_in[10];
  const float* Woff2 = (const float*)d_in[11];
  const float* btab  = (const float*)d_in[12];
  float* ws  = (float*)d_ws;
  float* out = (float*)d_out;

  k_weff<<<3, 256, 0, stream>>>(Woff1, Woff2, ws);
  k_weq<<<49, 256, 0, stream>>>(Wq, bq, Woff2, boff1, ws);
  k_z<<<256, 256, 0, stream>>>(x, ws + OFF_WEQ, ws + OFF_ZT);
  k_wx<<<(BB * GG * SS) / 256, 256, 0, stream>>>(ws);
  k_xw_part<<<256, 256, 0, stream>>>(x, ws);
  k_xw_red<<<84, 256, 0, stream>>>(ws);
  k_feat<<<16, 256, 0, stream>>>(x, ws);
  k_dots<<<13568, 256, 0, stream>>>(Wq, bq, Wk, Wv, Wo, ws);
  k_attn<<<1024, 256, 0, stream>>>(bk, bv, ws);
  k_wav<<<1024, 256, 0, stream>>>(Wo, bo, ws);
  k_out<<<256, 256, 0, stream>>>(btab, ws, out);
}

// Round 2
// 217.324 us; speedup vs baseline: 1.2418x; 1.2418x over previous
//
#include <hip/hip_runtime.h>
#include <math.h>

#define BB 4
#define SS 4096
#define DD 1024
#define HH 16
#define GG 4
#define KK 3
#define DG 256
#define DH 64

// ---- workspace layout (float offsets, all float4-aligned) ----
enum : size_t {
  OFF_WEFF  = 0,        // DG*KK = 768
  OFF_OFFC  = 1024,     // 4
  OFF_WEQ   = 1280,     // 12*DD = 12288   [j=g*3+k][c]
  OFF_ZT    = 13568,    // B*S*12 = 196608 [b][s][j]
  OFF_WX    = 210176,   // B*G*S = 65536   [b][g][s]
  OFF_XWP   = 275712,   // B*5*64*D = 1310720 partials [b][slot][ch][c]
  OFF_XW    = 1586432,  // B*G*D = 16384   [b][g][c]
  OFF_XS    = 1602816,  // B*D = 4096
  OFF_SW    = 1606912,  // B*G = 16 (padded)
  OFF_FEAT  = 1607168,  // B*D = 4096
  OFF_KF    = 1611264,  // B*G*D = 16384   [b][g][o]
  OFF_VF    = 1627648,  // B*G*D = 16384
  OFF_QW    = 1644032,  // B*D*G = 16384   [b][I][g]
  OFF_QS    = 1660416,  // B*D = 4096
  OFF_AV    = 1664512,  // B*D*G = 16384   [b][d][g]
  OFF_AB    = 1680896,  // B*D = 4096
  OFF_C2    = 1684992,  // B*D = 4096
  OFF_WAV   = 1689088,  // B*D*G = 16384   [b][o][g]
  OFF_WOSUM = 1705472,  // D = 1024
  WS_FLOATS = 1706496   // ~6.5 MB
};

__device__ __forceinline__ float wred_sum(float v) {
#pragma unroll
  for (int o = 32; o > 0; o >>= 1) v += __shfl_xor(v, o, 64);
  return v;
}
__device__ __forceinline__ float wred_max(float v) {
#pragma unroll
  for (int o = 32; o > 0; o >>= 1) v = fmaxf(v, __shfl_xor(v, o, 64));
  return v;
}

// ---- P1: Weff (wave/output), feat, WoSum — all independent of each other ----
// blocks [0,192): Weff   [192,208): feat   [208,464): WoSum
__global__ void k_pre1(const float* __restrict__ Woff1, const float* __restrict__ Woff2,
                       const float* __restrict__ x, const float* __restrict__ Wo,
                       float* __restrict__ ws) {
  const int t = threadIdx.x;
  const int lane = t & 63;
  if (blockIdx.x < 192) {                        // Weff[i][kk], one wave per output
    const int widx = (blockIdx.x * 256 + t) >> 6;   // 0..767
    const int i = widx / 3, kk = widx - 3 * i;
    float a = 0.f;
#pragma unroll
    for (int u = 0; u < 4; ++u) {
      const int cc = lane + 64 * u;
      a += Woff2[cc] * Woff1[(size_t)(cc * DG + i) * KK + kk];
    }
    a = wred_sum(a);
    if (lane == 0) ws[OFF_WEFF + widx] = a;
  } else if (blockIdx.x < 208) {                 // feat[b][c]
    const int gid = (blockIdx.x - 192) * 256 + t;  // 0..4095
    const int b = gid >> 10, c = gid & 1023;
    ws[OFF_FEAT + gid] = 0.5f * (x[((size_t)b * SS + 2047) * DD + c] +
                                 x[((size_t)b * SS + 2048) * DD + c]);
  } else {                                       // WoSum[o], wave per output
    const int o = ((blockIdx.x - 208) * 256 + t) >> 6;  // 0..1023
    const float4* wo = (const float4*)(Wo + (size_t)o * DD);
    float v = 0.f;
#pragma unroll
    for (int it = 0; it < 4; ++it) {
      const float4 a = wo[lane + 64 * it];
      v += a.x + a.y + a.z + a.w;
    }
    v = wred_sum(v);
    if (lane == 0) ws[OFF_WOSUM + o] = v;
  }
}

// ---- P2: Weq (192 wide blocks, 4-way i-split) + offc (block 192) ----
__global__ void k_pre2(const float* __restrict__ Wq, const float* __restrict__ bq,
                       const float* __restrict__ Woff2, const float* __restrict__ boff1,
                       float* __restrict__ ws) {
  const float* Weff = ws + OFF_WEFF;
  const int t = threadIdx.x;
  const int lane = t & 63;
  if (blockIdx.x < 192) {
    // block = (j, c-chunk of 64); threads: lane=c, q=i-quarter
    const int j = blockIdx.x >> 4;               // 0..11
    const int c0 = (blockIdx.x & 15) * 64;
    const int g = j / 3, kk = j - 3 * g;
    const int q = t >> 6;
    float a = 0.f;
#pragma unroll 4
    for (int ii = 0; ii < 64; ++ii) {
      const int i = q * 64 + ii;
      a += Weff[i * KK + kk] * Wq[(size_t)(g * DG + i) * DD + c0 + lane];
    }
    __shared__ float red[4][64];
    red[q][lane] = a;
    __syncthreads();
    if (q == 0) {
      const float v = red[0][lane] + red[1][lane] + red[2][lane] + red[3][lane];
      ws[OFF_WEQ + (size_t)j * DD + c0 + lane] = v;
    }
  } else {                                       // offc[g] on wave 0
    if (t >= 64) return;
    float beff = 0.f;
#pragma unroll
    for (int u = 0; u < 4; ++u) {
      const int cc = lane + 64 * u;
      beff += Woff2[cc] * boff1[cc];
    }
    beff = wred_sum(beff);
#pragma unroll
    for (int g = 0; g < 4; ++g) {
      float a = 0.f;
#pragma unroll
      for (int u = 0; u < 4; ++u) {
        const int i = lane + 64 * u;
        a += (Weff[i * 3 + 0] + Weff[i * 3 + 1] + Weff[i * 3 + 2]) * bq[g * DG + i];
      }
      a = wred_sum(a);
      if (lane == 0) ws[OFF_OFFC + g] = a + beff;
    }
  }
}

// ---- K1a: zt[b][s][j] = Weq[j,:] . x[b,s,:]  (wave per row, 8 rows/wave) ----
__global__ __launch_bounds__(256, 2) void k_z(const float* __restrict__ x,
                                              const float* __restrict__ weq,
                                              float* __restrict__ zt) {
  const int lane = threadIdx.x & 63;
  const int wave = (blockIdx.x * blockDim.x + threadIdx.x) >> 6;
  const int nwaves = (gridDim.x * blockDim.x) >> 6;
  float4 w[12][4];
#pragma unroll
  for (int j = 0; j < 12; ++j)
#pragma unroll
    for (int it = 0; it < 4; ++it)
      w[j][it] = *(const float4*)(weq + (size_t)j * DD + 4 * (lane + 64 * it));
  for (int row = wave; row < BB * SS; row += nwaves) {
    const float4* xr = (const float4*)(x + (size_t)row * DD);
    float4 xv[4];
#pragma unroll
    for (int it = 0; it < 4; ++it) xv[it] = xr[lane + 64 * it];
    float acc[12];
#pragma unroll
    for (int j = 0; j < 12; ++j) {
      float a = 0.f;
#pragma unroll
      for (int it = 0; it < 4; ++it)
        a += xv[it].x * w[j][it].x + xv[it].y * w[j][it].y +
             xv[it].z * w[j][it].z + xv[it].w * w[j][it].w;
      acc[j] = a;
    }
#pragma unroll
    for (int j = 0; j < 12; ++j) acc[j] = wred_sum(acc[j]);
    if (lane == 0) {
#pragma unroll
      for (int j = 0; j < 12; ++j) zt[(size_t)row * 12 + j] = acc[j];
    }
  }
}

// ---- K1b: offset -> tanh -> wx  (conv k=3 pad=1 over zt) ----
__global__ void k_wx(float* __restrict__ ws) {
  const int gid = blockIdx.x * blockDim.x + threadIdx.x;
  if (gid >= BB * GG * SS) return;
  const int s = gid & (SS - 1);
  const int g = (gid >> 12) & 3;
  const int b = gid >> 14;
  const float* z = ws + OFF_ZT + (size_t)b * SS * 12;
  float off = ws[OFF_OFFC + g];
  if (s > 0)      off += z[(size_t)(s - 1) * 12 + g * 3 + 0];
  off += z[(size_t)s * 12 + g * 3 + 1];
  if (s < SS - 1) off += z[(size_t)(s + 1) * 12 + g * 3 + 2];
  off = tanhf(off) * (float)KK;
  const float vg = 2.0f * ((float)s + off) / (float)(SS - 1) - 1.0f;
  const float ix = 0.5f * vg;
  float wv = 1.0f - fabsf(ix);
  wv = fminf(fmaxf(wv, 0.0f), 1.0f);
  ws[OFF_WX + (size_t)(b * GG + g) * SS + s] = wv;
}

// ---- K2: partial Xwp[b][slot][ch][c]; slots 0..3 = wx-weighted, 4 = plain sum ----
// float4 per thread, 64 s-rows per block, unroll 4 for MLP
__global__ __launch_bounds__(256) void k_xw_part(const float* __restrict__ x,
                                                 float* __restrict__ ws) {
  const float* wx = ws + OFF_WX;
  const int b = blockIdx.x >> 6;
  const int ch = blockIdx.x & 63;
  const int t = threadIdx.x;                     // c4 index: c = 4t..4t+3
  float4 aw[5] = {};                             // [slot]
  const int s0 = ch * 64;
#pragma unroll 4
  for (int si = 0; si < 64; ++si) {
    const int s = s0 + si;
    const float w0 = wx[(size_t)(b * GG + 0) * SS + s];
    const float w1 = wx[(size_t)(b * GG + 1) * SS + s];
    const float w2 = wx[(size_t)(b * GG + 2) * SS + s];
    const float w3 = wx[(size_t)(b * GG + 3) * SS + s];
    const float4 f = *(const float4*)(x + (size_t)(b * SS + s) * DD + 4 * t);
    aw[0].x += f.x * w0; aw[0].y += f.y * w0; aw[0].z += f.z * w0; aw[0].w += f.w * w0;
    aw[1].x += f.x * w1; aw[1].y += f.y * w1; aw[1].z += f.z * w1; aw[1].w += f.w * w1;
    aw[2].x += f.x * w2; aw[2].y += f.y * w2; aw[2].z += f.z * w2; aw[2].w += f.w * w2;
    aw[3].x += f.x * w3; aw[3].y += f.y * w3; aw[3].z += f.z * w3; aw[3].w += f.w * w3;
    aw[4].x += f.x; aw[4].y += f.y; aw[4].z += f.z; aw[4].w += f.w;
  }
  float* Xwp = ws + OFF_XWP;
#pragma unroll
  for (int slot = 0; slot < 5; ++slot)
    *(float4*)(Xwp + (((size_t)(b * 5 + slot) * 64 + ch) * DD) + 4 * t) = aw[slot];
}

// ---- K2b: reduce partials; blocks [0,320): Xw/Xs  [320,336): Sw ----
__global__ void k_xw_red(float* __restrict__ ws) {
  const int t = threadIdx.x;
  const int lane = t & 63;
  if (blockIdx.x < 320) {
    // block = (b, slot, c-chunk of 64): 4*5*16
    const int b = blockIdx.x / 80;
    const int rem = blockIdx.x - b * 80;
    const int slot = rem >> 4;
    const int c0 = (rem & 15) * 64;
    const int q = t >> 6;
    const float* base = ws + OFF_XWP + (size_t)(b * 5 + slot) * 64 * DD;
    float a = 0.f;
#pragma unroll 4
    for (int ii = 0; ii < 16; ++ii) {
      const int ch = q * 16 + ii;
      a += base[(size_t)ch * DD + c0 + lane];
    }
    __shared__ float red[4][64];
    red[q][lane] = a;
    __syncthreads();
    if (q == 0) {
      const float v = red[0][lane] + red[1][lane] + red[2][lane] + red[3][lane];
      if (slot < 4) ws[OFF_XW + ((size_t)(b * GG + slot)) * DD + c0 + lane] = v;
      else          ws[OFF_XS + (size_t)b * DD + c0 + lane] = v;
    }
  } else {                                       // Sw[b*4+g]
    const int w = blockIdx.x - 320;              // 0..15
    const float* wx = ws + OFF_WX + (size_t)w * SS;
    float a = 0.f;
#pragma unroll 4
    for (int it = 0; it < 16; ++it) a += wx[t + 256 * it];
    a = wred_sum(a);
    __shared__ float red[4];
    if (lane == 0) red[t >> 6] = a;
    __syncthreads();
    if (t == 0) ws[OFF_SW + w] = red[0] + red[1] + red[2] + red[3];
  }
}

// ---- K3: all small dot-products, one wave per output ----
// [0,16384): Kf   [16384,32768): Vf   [32768,49152): Qw   [49152,53248): Qs
__global__ void k_dots(const float* __restrict__ Wq, const float* __restrict__ bq,
                       const float* __restrict__ Wk, const float* __restrict__ Wv,
                       float* __restrict__ ws) {
  const int lane = threadIdx.x & 63;
  const int w = (blockIdx.x * blockDim.x + threadIdx.x) >> 6;
  if (w < 16384) {                               // Kf[b][g][o]
    const int o = w & 1023, g = (w >> 10) & 3, b = w >> 12;
    const float4 a = ((const float4*)(Wk + (size_t)o * DD + g * DG))[lane];
    const float4 f = ((const float4*)(ws + OFF_FEAT + b * DD + g * DG))[lane];
    float v = a.x * f.x + a.y * f.y + a.z * f.z + a.w * f.w;
    v = wred_sum(v);
    if (lane == 0) ws[OFF_KF + w] = v;
  } else if (w < 32768) {                        // Vf[b][g][o]
    const int i2 = w - 16384;
    const int o = i2 & 1023, g = (i2 >> 10) & 3, b = i2 >> 12;
    const float4 a = ((const float4*)(Wv + (size_t)o * DD + g * DG))[lane];
    const float4 f = ((const float4*)(ws + OFF_FEAT + b * DD + g * DG))[lane];
    float v = a.x * f.x + a.y * f.y + a.z * f.z + a.w * f.w;
    v = wred_sum(v);
    if (lane == 0) ws[OFF_VF + i2] = v;
  } else if (w < 49152) {                        // Qw[b][I][g]
    const int i2 = w - 32768;
    const int g = i2 & 3, I = (i2 >> 2) & 1023, b = i2 >> 12;
    const float4* wq = (const float4*)(Wq + (size_t)I * DD);
    const float4* xw = (const float4*)(ws + OFF_XW + (size_t)(b * GG + g) * DD);
    float v = 0.f;
#pragma unroll
    for (int it = 0; it < 4; ++it) {
      const float4 a = wq[lane + 64 * it], c = xw[lane + 64 * it];
      v += a.x * c.x + a.y * c.y + a.z * c.z + a.w * c.w;
    }
    v = wred_sum(v);
    if (lane == 0) ws[OFF_QW + i2] = v + bq[I] * ws[OFF_SW + b * GG + g];
  } else if (w < 53248) {                        // Qs[b][I]
    const int i2 = w - 49152;
    const int I = i2 & 1023, b = i2 >> 10;
    const float4* wq = (const float4*)(Wq + (size_t)I * DD);
    const float4* xs = (const float4*)(ws + OFF_XS + (size_t)b * DD);
    float v = 0.f;
#pragma unroll
    for (int it = 0; it < 4; ++it) {
      const float4 a = wq[lane + 64 * it], c = xs[lane + 64 * it];
      v += a.x * c.x + a.y * c.y + a.z * c.z + a.w * c.w;
    }
    v = wred_sum(v);
    if (lane == 0) ws[OFF_QS + i2] = v + (float)SS * bq[I];
  }
}

// ---- K4: scores -> softmax -> AV, Ab. One wave per (b, d) row; lane = j ----
__global__ void k_attn(const float* __restrict__ bk, const float* __restrict__ bv,
                       float* __restrict__ ws) {
  const int gid = blockIdx.x * blockDim.x + threadIdx.x;
  const int lane = gid & 63;
  const int w = gid >> 6;                        // w = b*1024 + d
  if (w >= BB * DD) return;
  const int b = w >> 10, d = w & 1023;
  const int hh = d >> 6;
  const int J = (hh << 6) | lane;
  const float* Qw = ws + OFF_QW + (size_t)w * 4;
  const float q0 = Qw[0], q1 = Qw[1], q2 = Qw[2], q3 = Qw[3];
  const float qs = ws[OFF_QS + w];
  const float* Kf = ws + OFF_KF + (size_t)b * GG * DD;
  float sc = q0 * Kf[0 * DD + J] + q1 * Kf[1 * DD + J] +
             q2 * Kf[2 * DD + J] + q3 * Kf[3 * DD + J] + bk[J] * qs;
  sc *= 0.03125f;                                // D^-0.5 = 1/32
  const float m = wred_max(sc);
  const float e = expf(sc - m);
  const float sum = wred_sum(e);
  const float attn = e / sum;
  const float* Vf = ws + OFF_VF + (size_t)b * GG * DD;
#pragma unroll
  for (int g = 0; g < 4; ++g) {
    const float av = wred_sum(attn * Vf[(size_t)g * DD + J]);
    if (lane == 0) ws[OFF_AV + (size_t)w * 4 + g] = av;
  }
  const float ab = wred_sum(attn * bv[J]);
  if (lane == 0) ws[OFF_AB + w] = ab;
}

// ---- K5: WAV[b,o,g] = sum_d Wo[o,d]*AV[b,d,g]; C2 = sum_d Wo*Ab + bo ----
__global__ void k_wav(const float* __restrict__ Wo, const float* __restrict__ bo,
                      float* __restrict__ ws) {
  const int gid = blockIdx.x * blockDim.x + threadIdx.x;
  const int lane = gid & 63;
  const int w = gid >> 6;                        // w = b*1024 + o
  if (w >= BB * DD) return;
  const int b = w >> 10, o = w & 1023;
  float acc0 = 0, acc1 = 0, acc2 = 0, acc3 = 0, acc4 = 0;
  const float4* wo4 = (const float4*)(Wo + (size_t)o * DD);
  const float* AV = ws + OFF_AV + (size_t)b * DD * 4;
  const float* Ab = ws + OFF_AB + (size_t)b * DD;
#pragma unroll
  for (int it = 0; it < 4; ++it) {
    const int d4 = lane + 64 * it;               // d = 4*d4 .. 4*d4+3
    const float4 wv = wo4[d4];
    const float4 a0 = *(const float4*)(AV + (size_t)(4 * d4 + 0) * 4);
    const float4 a1 = *(const float4*)(AV + (size_t)(4 * d4 + 1) * 4);
    const float4 a2 = *(const float4*)(AV + (size_t)(4 * d4 + 2) * 4);
    const float4 a3 = *(const float4*)(AV + (size_t)(4 * d4 + 3) * 4);
    acc0 += wv.x * a0.x + wv.y * a1.x + wv.z * a2.x + wv.w * a3.x;
    acc1 += wv.x * a0.y + wv.y * a1.y + wv.z * a2.y + wv.w * a3.y;
    acc2 += wv.x * a0.z + wv.y * a1.z + wv.z * a2.z + wv.w * a3.z;
    acc3 += wv.x * a0.w + wv.y * a1.w + wv.z * a2.w + wv.w * a3.w;
    const float4 abv = *(const float4*)(Ab + 4 * d4);
    acc4 += wv.x * abv.x + wv.y * abv.y + wv.z * abv.z + wv.w * abv.w;
  }
  acc0 = wred_sum(acc0); acc1 = wred_sum(acc1); acc2 = wred_sum(acc2);
  acc3 = wred_sum(acc3); acc4 = wred_sum(acc4);
  if (lane == 0) {
    float* WAV = ws + OFF_WAV + (size_t)w * 4;
    WAV[0] = acc0; WAV[1] = acc1; WAV[2] = acc2; WAV[3] = acc3;
    ws[OFF_C2 + w] = acc4 + bo[o];
  }
}

// ---- K6: out[b,s,o] = sum_g wx*WAV + C2 + bias_table[s]*WoSum (32-s chunks) ----
__global__ __launch_bounds__(256) void k_out(const float* __restrict__ btab,
                                             const float* __restrict__ ws,
                                             float* __restrict__ out) {
  const int b = blockIdx.x >> 7;
  const int ch = blockIdx.x & 127;
  const int t = threadIdx.x;
  const int o0 = 4 * t;
  float4 wav[4];
#pragma unroll
  for (int io = 0; io < 4; ++io)
    wav[io] = *(const float4*)(ws + OFF_WAV + (size_t)(b * DD + o0 + io) * 4);
  const float4 c24 = *(const float4*)(ws + OFF_C2 + (size_t)b * DD + o0);
  const float4 wos4 = *(const float4*)(ws + OFF_WOSUM + o0);
  const float* wx = ws + OFF_WX;
  const int s0 = ch * 32;
#pragma unroll 2
  for (int si = 0; si < 32; ++si) {
    const int s = s0 + si;
    const float w0 = wx[(size_t)(b * GG + 0) * SS + s];
    const float w1 = wx[(size_t)(b * GG + 1) * SS + s];
    const float w2 = wx[(size_t)(b * GG + 2) * SS + s];
    const float w3 = wx[(size_t)(b * GG + 3) * SS + s];
    const float bt = btab[s];
    float4 val;
    val.x = c24.x + bt * wos4.x + w0 * wav[0].x + w1 * wav[0].y + w2 * wav[0].z + w3 * wav[0].w;
    val.y = c24.y + bt * wos4.y + w0 * wav[1].x + w1 * wav[1].y + w2 * wav[1].z + w3 * wav[1].w;
    val.z = c24.z + bt * wos4.z + w0 * wav[2].x + w1 * wav[2].y + w2 * wav[2].z + w3 * wav[2].w;
    val.w = c24.w + bt * wos4.w + w0 * wav[3].x + w1 * wav[3].y + w2 * wav[3].z + w3 * wav[3].w;
    *(float4*)(out + (size_t)(b * SS + s) * DD + o0) = val;
  }
}

extern "C" void kernel_launch(void* const* d_in, const int* in_sizes, int n_in,
                              void* d_out, int out_size, void* d_ws, size_t ws_size,
                              hipStream_t stream) {
  const float* x     = (const float*)d_in[0];
  const float* Wq    = (const float*)d_in[1];
  const float* bq    = (const float*)d_in[2];
  const float* Wk    = (const float*)d_in[3];
  const float* bk    = (const float*)d_in[4];
  const float* Wv    = (const float*)d_in[5];
  const float* bv    = (const float*)d_in[6];
  const float* Wo    = (const float*)d_in[7];
  const float* bo    = (const float*)d_in[8];
  const float* Woff1 = (const float*)d_in[9];
  const float* boff1 = (const float*)d_in[10];
  const float* Woff2 = (const float*)d_in[11];
  const float* btab  = (const float*)d_in[12];
  float* ws  = (float*)d_ws;
  float* out = (float*)d_out;

  k_pre1<<<464, 256, 0, stream>>>(Woff1, Woff2, x, Wo, ws);
  k_pre2<<<193, 256, 0, stream>>>(Wq, bq, Woff2, boff1, ws);
  k_z<<<512, 256, 0, stream>>>(x, ws + OFF_WEQ, ws + OFF_ZT);
  k_wx<<<(BB * GG * SS) / 256, 256, 0, stream>>>(ws);
  k_xw_part<<<256, 256, 0, stream>>>(x, ws);
  k_xw_red<<<336, 256, 0, stream>>>(ws);
  k_dots<<<13312, 256, 0, stream>>>(Wq, bq, Wk, Wv, ws);
  k_attn<<<1024, 256, 0, stream>>>(bk, bv, ws);
  k_wav<<<1024, 256, 0, stream>>>(Wo, bo, ws);
  k_out<<<512, 256, 0, stream>>>(btab, ws, out);
}